// Round 2
// baseline (383.158 us; speedup 1.0000x reference)
//
#include <hip/hip_runtime.h>
#include <hip/hip_bf16.h>
#include <stdint.h>

#define DEV __device__ __forceinline__

typedef __attribute__((ext_vector_type(8))) short short8;
typedef __attribute__((ext_vector_type(8))) __bf16 bf16x8;
typedef __attribute__((ext_vector_type(4))) float f32x4;

typedef const __attribute__((address_space(1))) uint32_t gu32;
typedef __attribute__((address_space(3))) uint32_t lu32;

DEV void gload16(const void* g, void* l) {
  __builtin_amdgcn_global_load_lds((gu32*)g, (lu32*)l, 16, 0, 0);
}

DEV f32x4 mfma16(bf16x8 a, bf16x8 b, f32x4 c) {
  return __builtin_amdgcn_mfma_f32_16x16x32_bf16(a, b, c, 0, 0, 0);
}

DEV __hip_bfloat16 f2bf(float x) { return __float2bfloat16(x); }
DEV bf16x8 as_bf(short8 v) { union { short8 s; bf16x8 b; } u; u.s = v; return u.b; }

// ---------------------------------------------------------------------------
// f32 -> bf16 elementwise convert (n multiple of 8).
// ---------------------------------------------------------------------------
__global__ __launch_bounds__(256)
void cvt_f32_bf16(const float* __restrict__ src, __hip_bfloat16* __restrict__ dst, int n)
{
  int i = (blockIdx.x * 256 + threadIdx.x) * 8;
  if (i >= n) return;
  f32x4 a = *(const f32x4*)&src[i];
  f32x4 b = *(const f32x4*)&src[i + 4];
  short8 o;
#pragma unroll
  for (int j = 0; j < 4; ++j) {
    o[j]     = __bfloat16_as_short(f2bf(a[j]));
    o[j + 4] = __bfloat16_as_short(f2bf(b[j]));
  }
  *(short8*)&dst[i] = o;
}

// ---------------------------------------------------------------------------
// Transpose f32 [K][N] -> bf16 [N][K], 64x64 tiles, 256 threads.
// ---------------------------------------------------------------------------
__global__ __launch_bounds__(256)
void transpose_cvt(const float* __restrict__ src,
                   __hip_bfloat16* __restrict__ dst,
                   int K, int N)
{
  __shared__ __hip_bfloat16 tile[64][72];
  const int tid = threadIdx.x;
  const int k0 = blockIdx.y * 64, n0 = blockIdx.x * 64;
  const int r = tid >> 3, c8 = tid & 7;
#pragma unroll
  for (int i = 0; i < 2; ++i) {
    int k = r + i * 32;
    f32x4 a = *(const f32x4*)&src[(size_t)(k0 + k) * N + n0 + c8 * 8];
    f32x4 b = *(const f32x4*)&src[(size_t)(k0 + k) * N + n0 + c8 * 8 + 4];
#pragma unroll
    for (int j = 0; j < 4; ++j) {
      tile[k][c8 * 8 + j]     = f2bf(a[j]);
      tile[k][c8 * 8 + 4 + j] = f2bf(b[j]);
    }
  }
  __syncthreads();
#pragma unroll
  for (int i = 0; i < 2; ++i) {
    int n = r + i * 32;
    short8 v;
#pragma unroll
    for (int j = 0; j < 8; ++j) v[j] = *(const short*)&tile[c8 * 8 + j][n];
    *(short8*)&dst[(size_t)(n0 + n) * K + k0 + c8 * 8] = v;
  }
}

// ---------------------------------------------------------------------------
// GEMM: C[M][N] = A[M][K](bf16) * Bt[N][K](bf16)^T + bias[N](f32)
// 128x128 tile, BK=64, 4 waves (2x2), 16x16x32 bf16 MFMA, global_load_lds,
// XOR-swizzled LDS (linear dest + inverse-swizzled global src + swizzled read).
// mode 0: write C (f32).  mode 1: scatter to q/k/v^T bf16 buffers (QKV proj).
// ---------------------------------------------------------------------------
__global__ __launch_bounds__(256)
void gemm_bt(const __hip_bfloat16* __restrict__ A,
             const __hip_bfloat16* __restrict__ Bt,
             const float* __restrict__ bias,
             float* __restrict__ C,
             __hip_bfloat16* __restrict__ qb,
             __hip_bfloat16* __restrict__ kb,
             __hip_bfloat16* __restrict__ vtb,
             int M, int N, int K, int mode)
{
  __shared__ __hip_bfloat16 As[128 * 64];
  __shared__ __hip_bfloat16 Bs[128 * 64];

  const int tid = threadIdx.x;
  const int lane = tid & 63;
  const int wave = tid >> 6;
  const int wm = wave >> 1, wn = wave & 1;
  const int m0 = blockIdx.y * 128, n0 = blockIdx.x * 128;
  const int fr = lane & 15, fq = lane >> 4;

  const int sc = wave * 4;
  const int srow = lane >> 3;   // row within 8-row chunk
  const int scol = lane & 7;    // 16B slot within 128B row

  f32x4 acc[4][4] = {};
  const char* Ab = (const char*)As;
  const char* Bb = (const char*)Bs;

  for (int k0 = 0; k0 < K; k0 += 64) {
#pragma unroll
    for (int i = 0; i < 4; ++i) {
      int c = sc + i;
      int rr = c * 8 + srow;
      int kk = (scol ^ (rr & 7)) << 3;
      gload16(&A[(size_t)(m0 + rr) * K + k0 + kk], &As[c * 512]);
    }
#pragma unroll
    for (int i = 0; i < 4; ++i) {
      int c = sc + i;
      int rr = c * 8 + srow;
      int kk = (scol ^ (rr & 7)) << 3;
      gload16(&Bt[(size_t)(n0 + rr) * K + k0 + kk], &Bs[c * 512]);
    }
    __syncthreads();
#pragma unroll
    for (int kk = 0; kk < 2; ++kk) {
      bf16x8 af[4], bfv[4];
#pragma unroll
      for (int mi = 0; mi < 4; ++mi) {
        int row = wm * 64 + mi * 16 + fr;
        int cb = (kk * 64 + fq * 16) ^ ((row & 7) << 4);
        af[mi] = as_bf(*(const short8*)(Ab + row * 128 + cb));
      }
#pragma unroll
      for (int ni = 0; ni < 4; ++ni) {
        int row = wn * 64 + ni * 16 + fr;
        int cb = (kk * 64 + fq * 16) ^ ((row & 7) << 4);
        bfv[ni] = as_bf(*(const short8*)(Bb + row * 128 + cb));
      }
#pragma unroll
      for (int mi = 0; mi < 4; ++mi)
#pragma unroll
        for (int ni = 0; ni < 4; ++ni)
          acc[mi][ni] = mfma16(af[mi], bfv[ni], acc[mi][ni]);
    }
    __syncthreads();
  }

  if (mode == 0) {
#pragma unroll
    for (int ni = 0; ni < 4; ++ni) {
      int n = n0 + wn * 64 + ni * 16 + fr;
      float bv = bias[n];
#pragma unroll
      for (int mi = 0; mi < 4; ++mi) {
        int mbase = m0 + wm * 64 + mi * 16 + fq * 4;
#pragma unroll
        for (int j = 0; j < 4; ++j)
          C[(size_t)(mbase + j) * N + n] = acc[mi][ni][j] + bv;
      }
    }
  } else {
    // n0 is a multiple of 128; 384 = 3*128 so head h and q/k/v type t are
    // uniform for the whole block.
    const int h = n0 / 384;
    const int t = (n0 % 384) >> 7;
#pragma unroll
    for (int ni = 0; ni < 4; ++ni) {
      int dloc = wn * 64 + ni * 16 + fr;   // 0..127 == head-dim index d
      int n = n0 + dloc;
      float bv = bias[n];
#pragma unroll
      for (int mi = 0; mi < 4; ++mi) {
        int mbase = m0 + wm * 64 + mi * 16 + fq * 4;
#pragma unroll
        for (int j = 0; j < 4; ++j) {
          int m = mbase + j;
          int b = m >> 11, s = m & 2047;
          int bh = b * 16 + h;
          float v = acc[mi][ni][j] + bv;
          if (t == 0)      qb[((size_t)bh * 2048 + s) * 128 + dloc] = f2bf(v);
          else if (t == 1) kb[((size_t)bh * 2048 + s) * 128 + dloc] = f2bf(v);
          else             vtb[((size_t)bh * 128 + dloc) * 2048 + s] = f2bf(v);
        }
      }
    }
  }
}

// ---------------------------------------------------------------------------
// Causal flash attention. Grid: (32 q-tiles of 64 rows, 32 bh). 256 threads.
// Each wave owns 16 q rows. K tiles [64][128] and V^T tiles [128][64] staged
// in swizzled LDS via global_load_lds; P staged per-wave in swizzled LDS.
// ---------------------------------------------------------------------------
__global__ __launch_bounds__(256)
void attn_kernel(const __hip_bfloat16* __restrict__ qb,
                 const __hip_bfloat16* __restrict__ kb,
                 const __hip_bfloat16* __restrict__ vtb,
                 __hip_bfloat16* __restrict__ ctx)
{
  __shared__ __hip_bfloat16 Ks[64 * 128];
  __shared__ __hip_bfloat16 Vts[128 * 64];
  __shared__ __hip_bfloat16 Ps[4][16 * 64];

  const int tid = threadIdx.x, lane = tid & 63, wave = tid >> 6;
  const int fr = lane & 15, fq = lane >> 4;
  const int bh = blockIdx.y;
  const int q0 = blockIdx.x * 64;

  // Q fragments (A operand): row = lane&15 within this wave's 16-row window
  bf16x8 qf[4];
  const int qrow = q0 + wave * 16 + fr;
#pragma unroll
  for (int kf = 0; kf < 4; ++kf)
    qf[kf] = as_bf(*(const short8*)&qb[((size_t)bh * 2048 + qrow) * 128 + kf * 32 + fq * 8]);

  f32x4 acco[8] = {};
  float m_run[4] = {-1e30f, -1e30f, -1e30f, -1e30f};
  float l_run[4] = {0.f, 0.f, 0.f, 0.f};

  const char* Kb = (const char*)Ks;
  const char* Vb = (const char*)Vts;
  char* Pb = (char*)&Ps[wave][0];

  const int ntiles = q0 / 64 + 1;
  for (int t = 0; t < ntiles; ++t) {
    const int k0 = t * 64;
    // stage K tile [64][128]
#pragma unroll
    for (int i = 0; i < 4; ++i) {
      int c = wave * 4 + i;
      int kv = c * 4 + fq;
      int cb = (fr * 16) ^ ((kv & 7) << 4);
      gload16(&kb[((size_t)bh * 2048 + k0 + kv) * 128 + (cb >> 1)], &Ks[c * 512]);
    }
    // stage V^T tile [128][64]
#pragma unroll
    for (int i = 0; i < 4; ++i) {
      int c = wave * 4 + i;
      int d = c * 8 + (lane >> 3);
      int cb = ((lane & 7) * 16) ^ ((d & 7) << 4);
      gload16(&vtb[((size_t)bh * 128 + d) * 2048 + k0 + (cb >> 1)], &Vts[c * 512]);
    }
    __syncthreads();

    // QK^T: 16 q rows x 64 kv
    f32x4 sacc[4] = {};
#pragma unroll
    for (int kf = 0; kf < 4; ++kf) {
#pragma unroll
      for (int ni = 0; ni < 4; ++ni) {
        int kv = ni * 16 + fr;
        int cb = (kf * 64 + fq * 16) ^ ((kv & 7) << 4);
        bf16x8 kfr = as_bf(*(const short8*)(Kb + kv * 256 + cb));
        sacc[ni] = mfma16(qf[kf], kfr, sacc[ni]);
      }
    }

    // scale + causal mask (reference: scale, then masked -> -10000 exactly)
    const float scale = 0.088388347648318447f;
    float sv[4][4];
    float rmax[4] = {-1e30f, -1e30f, -1e30f, -1e30f};
#pragma unroll
    for (int ni = 0; ni < 4; ++ni) {
      int kv_g = k0 + ni * 16 + fr;
#pragma unroll
      for (int j = 0; j < 4; ++j) {
        int q_g = q0 + wave * 16 + fq * 4 + j;
        float s = sacc[ni][j] * scale;
        if (kv_g > q_g) s = -10000.f;
        sv[ni][j] = s;
        rmax[j] = fmaxf(rmax[j], s);
      }
    }
#pragma unroll
    for (int off = 1; off < 16; off <<= 1)
#pragma unroll
      for (int j = 0; j < 4; ++j)
        rmax[j] = fmaxf(rmax[j], __shfl_xor(rmax[j], off));

    float alpha[4], rsum[4];
#pragma unroll
    for (int j = 0; j < 4; ++j) {
      float mn = fmaxf(m_run[j], rmax[j]);
      alpha[j] = __expf(m_run[j] - mn);
      m_run[j] = mn;
      rsum[j] = 0.f;
    }
#pragma unroll
    for (int ni = 0; ni < 4; ++ni) {
#pragma unroll
      for (int j = 0; j < 4; ++j) {
        float p = __expf(sv[ni][j] - m_run[j]);
        rsum[j] += p;
        int prow = fq * 4 + j;
        int cbw = ((ni * 16 + fr) * 2) ^ ((prow & 7) << 4);
        *(__hip_bfloat16*)(Pb + prow * 128 + cbw) = f2bf(p);
      }
    }
#pragma unroll
    for (int off = 1; off < 16; off <<= 1)
#pragma unroll
      for (int j = 0; j < 4; ++j)
        rsum[j] += __shfl_xor(rsum[j], off);
#pragma unroll
    for (int j = 0; j < 4; ++j)
      l_run[j] = l_run[j] * alpha[j] + rsum[j];

    // rescale running output
#pragma unroll
    for (int nd = 0; nd < 8; ++nd)
#pragma unroll
      for (int j = 0; j < 4; ++j)
        acco[nd][j] *= alpha[j];

    // P writes (per-wave LDS) must land before this wave's PV reads
    asm volatile("s_waitcnt lgkmcnt(0)" ::: "memory");

    // PV: acco += P[16x64] * V[64x128]
#pragma unroll
    for (int kf2 = 0; kf2 < 2; ++kf2) {
      int cbp = (kf2 * 64 + fq * 16) ^ ((fr & 7) << 4);
      bf16x8 pa = as_bf(*(const short8*)(Pb + fr * 128 + cbp));
#pragma unroll
      for (int nd = 0; nd < 8; ++nd) {
        int d = nd * 16 + fr;
        int cbv = (kf2 * 64 + fq * 16) ^ ((d & 7) << 4);
        bf16x8 vfr = as_bf(*(const short8*)(Vb + d * 128 + cbv));
        acco[nd] = mfma16(pa, vfr, acco[nd]);
      }
    }
    __syncthreads();
  }

  // epilogue: ctx[b][s][h][d]
  const int b = bh >> 4, h = bh & 15;
#pragma unroll
  for (int j = 0; j < 4; ++j) {
    float inv = 1.f / l_run[j];
    int s = q0 + wave * 16 + fq * 4 + j;
#pragma unroll
    for (int nd = 0; nd < 8; ++nd) {
      int d = nd * 16 + fr;
      ctx[(((size_t)b * 2048 + s) * 16 + h) * 128 + d] = f2bf(acco[nd][j] * inv);
    }
  }
}

// ---------------------------------------------------------------------------
extern "C" void kernel_launch(void* const* d_in, const int* in_sizes, int n_in,
                              void* d_out, int out_size, void* d_ws, size_t ws_size,
                              hipStream_t stream)
{
  (void)in_sizes; (void)n_in; (void)out_size; (void)ws_size;
  const float* x       = (const float*)d_in[0];
  const float* w_qkv   = (const float*)d_in[1];
  const float* b_qkv   = (const float*)d_in[2];
  const float* w_dense = (const float*)d_in[3];
  const float* b_dense = (const float*)d_in[4];
  float* out = (float*)d_out;

  char* ws = (char*)d_ws;
  __hip_bfloat16* x_bf     = (__hip_bfloat16*)(ws);                  // 4096x2048   = 16MB
  __hip_bfloat16* wqkv_t   = (__hip_bfloat16*)(ws + 16777216);       // 6144x2048   = 24MB
  __hip_bfloat16* wdense_t = (__hip_bfloat16*)(ws + 41943040);       // 2048x2048   = 8MB
  __hip_bfloat16* qb       = (__hip_bfloat16*)(ws + 50331648);       // [32][2048][128] = 16MB
  __hip_bfloat16* kb       = (__hip_bfloat16*)(ws + 67108864);       // [32][2048][128] = 16MB
  __hip_bfloat16* vtb      = (__hip_bfloat16*)(ws + 83886080);       // [32][128][2048] = 16MB
  __hip_bfloat16* ctx      = (__hip_bfloat16*)(ws + 100663296);      // [4096][2048] = 16MB

  cvt_f32_bf16<<<4096, 256, 0, stream>>>(x, x_bf, 4096 * 2048);
  transpose_cvt<<<dim3(96, 32), 256, 0, stream>>>(w_qkv, wqkv_t, 2048, 6144);
  transpose_cvt<<<dim3(32, 32), 256, 0, stream>>>(w_dense, wdense_t, 2048, 2048);
  gemm_bt<<<dim3(48, 32), 256, 0, stream>>>(x_bf, wqkv_t, b_qkv, nullptr,
                                            qb, kb, vtb, 4096, 6144, 2048, 1);
  attn_kernel<<<dim3(32, 32), 256, 0, stream>>>(qb, kb, vtb, ctx);
  gemm_bt<<<dim3(16, 32), 256, 0, stream>>>(ctx, wdense_t, b_dense, out,
                                            nullptr, nullptr, nullptr, 4096, 2048, 2048, 0);
}

// Round 3
// 300.151 us; speedup vs baseline: 1.2766x; 1.2766x over previous
//
#include <hip/hip_runtime.h>
#include <hip/hip_bf16.h>
#include <stdint.h>

#define DEV __device__ __forceinline__

typedef __attribute__((ext_vector_type(8))) short short8;
typedef __attribute__((ext_vector_type(8))) __bf16 bf16x8;
typedef __attribute__((ext_vector_type(4))) float f32x4;

typedef const __attribute__((address_space(1))) uint32_t gu32;
typedef __attribute__((address_space(3))) uint32_t lu32;

DEV void gload16(const void* g, void* l) {
  __builtin_amdgcn_global_load_lds((gu32*)g, (lu32*)l, 16, 0, 0);
}

DEV f32x4 mfma16(bf16x8 a, bf16x8 b, f32x4 c) {
  return __builtin_amdgcn_mfma_f32_16x16x32_bf16(a, b, c, 0, 0, 0);
}

DEV __hip_bfloat16 f2bf(float x) { return __float2bfloat16(x); }
DEV bf16x8 as_bf(short8 v) { union { short8 s; bf16x8 b; } u; u.s = v; return u.b; }

// ---------------------------------------------------------------------------
// f32 -> bf16 elementwise convert (n multiple of 8).
// ---------------------------------------------------------------------------
__global__ __launch_bounds__(256)
void cvt_f32_bf16(const float* __restrict__ src, __hip_bfloat16* __restrict__ dst, int n)
{
  int i = (blockIdx.x * 256 + threadIdx.x) * 8;
  if (i >= n) return;
  f32x4 a = *(const f32x4*)&src[i];
  f32x4 b = *(const f32x4*)&src[i + 4];
  short8 o;
#pragma unroll
  for (int j = 0; j < 4; ++j) {
    o[j]     = __bfloat16_as_short(f2bf(a[j]));
    o[j + 4] = __bfloat16_as_short(f2bf(b[j]));
  }
  *(short8*)&dst[i] = o;
}

// ---------------------------------------------------------------------------
// Transpose f32 [K][N] -> bf16 [N][K], 64x64 tiles, 256 threads.
// ---------------------------------------------------------------------------
__global__ __launch_bounds__(256)
void transpose_cvt(const float* __restrict__ src,
                   __hip_bfloat16* __restrict__ dst,
                   int K, int N)
{
  __shared__ __hip_bfloat16 tile[64][72];
  const int tid = threadIdx.x;
  const int k0 = blockIdx.y * 64, n0 = blockIdx.x * 64;
  const int r = tid >> 3, c8 = tid & 7;
#pragma unroll
  for (int i = 0; i < 2; ++i) {
    int k = r + i * 32;
    f32x4 a = *(const f32x4*)&src[(size_t)(k0 + k) * N + n0 + c8 * 8];
    f32x4 b = *(const f32x4*)&src[(size_t)(k0 + k) * N + n0 + c8 * 8 + 4];
#pragma unroll
    for (int j = 0; j < 4; ++j) {
      tile[k][c8 * 8 + j]     = f2bf(a[j]);
      tile[k][c8 * 8 + 4 + j] = f2bf(b[j]);
    }
  }
  __syncthreads();
#pragma unroll
  for (int i = 0; i < 2; ++i) {
    int n = r + i * 32;
    short8 v;
#pragma unroll
    for (int j = 0; j < 8; ++j) v[j] = *(const short*)&tile[c8 * 8 + j][n];
    *(short8*)&dst[(size_t)(n0 + n) * K + k0 + c8 * 8] = v;
  }
}

// ---------------------------------------------------------------------------
// GEMM: C[M][N] = A[M][K](bf16) * Bt[N][K](bf16)^T + bias[N](f32)
// 128x128 tile, BK=64, 4 waves (2x2), 16x16x32 bf16 MFMA, global_load_lds,
// XOR-swizzled LDS (linear dest + inverse-swizzled global src + swizzled read).
// mode 0: write C (f32).  mode 1: scatter to q/k/v^T bf16 buffers (QKV proj).
// ---------------------------------------------------------------------------
__global__ __launch_bounds__(256)
void gemm_bt(const __hip_bfloat16* __restrict__ A,
             const __hip_bfloat16* __restrict__ Bt,
             const float* __restrict__ bias,
             float* __restrict__ C,
             __hip_bfloat16* __restrict__ qb,
             __hip_bfloat16* __restrict__ kb,
             __hip_bfloat16* __restrict__ vtb,
             int M, int N, int K, int mode)
{
  __shared__ __hip_bfloat16 As[128 * 64];
  __shared__ __hip_bfloat16 Bs[128 * 64];

  const int tid = threadIdx.x;
  const int lane = tid & 63;
  const int wave = tid >> 6;
  const int wm = wave >> 1, wn = wave & 1;
  const int m0 = blockIdx.y * 128, n0 = blockIdx.x * 128;
  const int fr = lane & 15, fq = lane >> 4;

  const int sc = wave * 4;
  const int srow = lane >> 3;   // row within 8-row chunk
  const int scol = lane & 7;    // 16B slot within 128B row

  f32x4 acc[4][4] = {};
  const char* Ab = (const char*)As;
  const char* Bb = (const char*)Bs;

  for (int k0 = 0; k0 < K; k0 += 64) {
#pragma unroll
    for (int i = 0; i < 4; ++i) {
      int c = sc + i;
      int rr = c * 8 + srow;
      int kk = (scol ^ (rr & 7)) << 3;
      gload16(&A[(size_t)(m0 + rr) * K + k0 + kk], &As[c * 512]);
    }
#pragma unroll
    for (int i = 0; i < 4; ++i) {
      int c = sc + i;
      int rr = c * 8 + srow;
      int kk = (scol ^ (rr & 7)) << 3;
      gload16(&Bt[(size_t)(n0 + rr) * K + k0 + kk], &Bs[c * 512]);
    }
    __syncthreads();
#pragma unroll
    for (int kk = 0; kk < 2; ++kk) {
      bf16x8 af[4], bfv[4];
#pragma unroll
      for (int mi = 0; mi < 4; ++mi) {
        int row = wm * 64 + mi * 16 + fr;
        int cb = (kk * 64 + fq * 16) ^ ((row & 7) << 4);
        af[mi] = as_bf(*(const short8*)(Ab + row * 128 + cb));
      }
#pragma unroll
      for (int ni = 0; ni < 4; ++ni) {
        int row = wn * 64 + ni * 16 + fr;
        int cb = (kk * 64 + fq * 16) ^ ((row & 7) << 4);
        bfv[ni] = as_bf(*(const short8*)(Bb + row * 128 + cb));
      }
#pragma unroll
      for (int mi = 0; mi < 4; ++mi)
#pragma unroll
        for (int ni = 0; ni < 4; ++ni)
          acc[mi][ni] = mfma16(af[mi], bfv[ni], acc[mi][ni]);
    }
    __syncthreads();
  }

  if (mode == 0) {
#pragma unroll
    for (int ni = 0; ni < 4; ++ni) {
      int n = n0 + wn * 64 + ni * 16 + fr;
      float bv = bias[n];
#pragma unroll
      for (int mi = 0; mi < 4; ++mi) {
        int mbase = m0 + wm * 64 + mi * 16 + fq * 4;
#pragma unroll
        for (int j = 0; j < 4; ++j)
          C[(size_t)(mbase + j) * N + n] = acc[mi][ni][j] + bv;
      }
    }
  } else {
    const int h = n0 / 384;
    const int t = (n0 % 384) >> 7;
#pragma unroll
    for (int ni = 0; ni < 4; ++ni) {
      int dloc = wn * 64 + ni * 16 + fr;   // 0..127 == head-dim index d
      int n = n0 + dloc;
      float bv = bias[n];
#pragma unroll
      for (int mi = 0; mi < 4; ++mi) {
        int mbase = m0 + wm * 64 + mi * 16 + fq * 4;
#pragma unroll
        for (int j = 0; j < 4; ++j) {
          int m = mbase + j;
          int b = m >> 11, s = m & 2047;
          int bh = b * 16 + h;
          float v = acc[mi][ni][j] + bv;
          if (t == 0)      qb[((size_t)bh * 2048 + s) * 128 + dloc] = f2bf(v);
          else if (t == 1) kb[((size_t)bh * 2048 + s) * 128 + dloc] = f2bf(v);
          else             vtb[((size_t)bh * 128 + dloc) * 2048 + s] = f2bf(v);
        }
      }
    }
  }
}

// ---------------------------------------------------------------------------
// Causal flash attention v3.
// 1-D grid of 1024 blocks, HEAVY-FIRST: qi = 31 - (blk>>5), bh = blk&31.
// 4 waves x 16 q-rows, KV tiles of 64, DOUBLE-BUFFERED K/V staging (72KB LDS
// -> 2 blocks/CU -> 512 slots for 1024 blocks: light blocks backfill the
// tail left by heavy causal blocks). setprio(1) around MFMA clusters (T5).
// ---------------------------------------------------------------------------
__global__ __launch_bounds__(256)
void attn_kernel(const __hip_bfloat16* __restrict__ qb,
                 const __hip_bfloat16* __restrict__ kb,
                 const __hip_bfloat16* __restrict__ vtb,
                 __hip_bfloat16* __restrict__ ctx)
{
  __shared__ __hip_bfloat16 Ks[2][64 * 128];
  __shared__ __hip_bfloat16 Vts[2][128 * 64];
  __shared__ __hip_bfloat16 Ps[4][16 * 64];

  const int tid = threadIdx.x, lane = tid & 63, wave = tid >> 6;
  const int fr = lane & 15, fq = lane >> 4;
  const int blk = blockIdx.x;
  const int qi = 31 - (blk >> 5);      // heavy blocks dispatched first
  const int bh = blk & 31;
  const int q0 = qi * 64;

  // Q fragments (A operand): row = lane&15 within this wave's 16-row window
  bf16x8 qf[4];
  const int qrow = q0 + wave * 16 + fr;
#pragma unroll
  for (int kf = 0; kf < 4; ++kf)
    qf[kf] = as_bf(*(const short8*)&qb[((size_t)bh * 2048 + qrow) * 128 + kf * 32 + fq * 8]);

  f32x4 acco[8] = {};
  float m_run[4] = {-1e30f, -1e30f, -1e30f, -1e30f};
  float l_run[4] = {0.f, 0.f, 0.f, 0.f};

  char* Pb = (char*)&Ps[wave][0];
  const int nt = qi + 1;

  auto STAGE = [&](int t, int buf) {
    const int k0t = t * 64;
#pragma unroll
    for (int i = 0; i < 4; ++i) {
      int c = wave * 4 + i;
      int kv = c * 4 + fq;
      int cb = (fr * 16) ^ ((kv & 7) << 4);
      gload16(&kb[((size_t)bh * 2048 + k0t + kv) * 128 + (cb >> 1)], &Ks[buf][c * 512]);
    }
#pragma unroll
    for (int i = 0; i < 4; ++i) {
      int c = wave * 4 + i;
      int d = c * 8 + (lane >> 3);
      int cb = ((lane & 7) * 16) ^ ((d & 7) << 4);
      gload16(&vtb[((size_t)bh * 128 + d) * 2048 + k0t + (cb >> 1)], &Vts[buf][c * 512]);
    }
  };

  STAGE(0, 0);
  __syncthreads();

  int cur = 0;
  for (int t = 0; t < nt; ++t) {
    if (t + 1 < nt) STAGE(t + 1, cur ^ 1);   // prefetch next tile (T3)
    const char* Kb = (const char*)&Ks[cur][0];
    const char* Vb = (const char*)&Vts[cur][0];
    const int k0 = t * 64;

    // QK^T: 16 q rows x 64 kv
    f32x4 sacc[4] = {};
    __builtin_amdgcn_s_setprio(1);
#pragma unroll
    for (int kf = 0; kf < 4; ++kf) {
#pragma unroll
      for (int ni = 0; ni < 4; ++ni) {
        int kv = ni * 16 + fr;
        int cb = (kf * 64 + fq * 16) ^ ((kv & 7) << 4);
        bf16x8 kfr = as_bf(*(const short8*)(Kb + kv * 256 + cb));
        sacc[ni] = mfma16(qf[kf], kfr, sacc[ni]);
      }
    }
    __builtin_amdgcn_s_setprio(0);

    // scale + causal mask (reference: scale, then masked -> -10000 exactly)
    const float scale = 0.088388347648318447f;
    float sv[4][4];
    float rmax[4] = {-1e30f, -1e30f, -1e30f, -1e30f};
#pragma unroll
    for (int ni = 0; ni < 4; ++ni) {
      int kv_g = k0 + ni * 16 + fr;
#pragma unroll
      for (int j = 0; j < 4; ++j) {
        int q_g = q0 + wave * 16 + fq * 4 + j;
        float s = sacc[ni][j] * scale;
        if (kv_g > q_g) s = -10000.f;
        sv[ni][j] = s;
        rmax[j] = fmaxf(rmax[j], s);
      }
    }
#pragma unroll
    for (int off = 1; off < 16; off <<= 1)
#pragma unroll
      for (int j = 0; j < 4; ++j)
        rmax[j] = fmaxf(rmax[j], __shfl_xor(rmax[j], off));

    float alpha[4], rsum[4];
#pragma unroll
    for (int j = 0; j < 4; ++j) {
      float mn = fmaxf(m_run[j], rmax[j]);
      alpha[j] = __expf(m_run[j] - mn);
      m_run[j] = mn;
      rsum[j] = 0.f;
    }
#pragma unroll
    for (int ni = 0; ni < 4; ++ni) {
#pragma unroll
      for (int j = 0; j < 4; ++j) {
        float p = __expf(sv[ni][j] - m_run[j]);
        rsum[j] += p;
        int prow = fq * 4 + j;
        int cbw = ((ni * 16 + fr) * 2) ^ ((prow & 7) << 4);
        *(__hip_bfloat16*)(Pb + prow * 128 + cbw) = f2bf(p);
      }
    }
#pragma unroll
    for (int off = 1; off < 16; off <<= 1)
#pragma unroll
      for (int j = 0; j < 4; ++j)
        rsum[j] += __shfl_xor(rsum[j], off);
#pragma unroll
    for (int j = 0; j < 4; ++j)
      l_run[j] = l_run[j] * alpha[j] + rsum[j];

    // rescale running output
#pragma unroll
    for (int nd = 0; nd < 8; ++nd)
#pragma unroll
      for (int j = 0; j < 4; ++j)
        acco[nd][j] *= alpha[j];

    // P writes (per-wave LDS) must land before this wave's PV reads
    asm volatile("s_waitcnt lgkmcnt(0)" ::: "memory");
    __builtin_amdgcn_sched_barrier(0);

    // PV: acco += P[16x64] * V[64x128]
    __builtin_amdgcn_s_setprio(1);
#pragma unroll
    for (int kf2 = 0; kf2 < 2; ++kf2) {
      int cbp = (kf2 * 64 + fq * 16) ^ ((fr & 7) << 4);
      bf16x8 pa = as_bf(*(const short8*)(Pb + fr * 128 + cbp));
#pragma unroll
      for (int nd = 0; nd < 8; ++nd) {
        int d = nd * 16 + fr;
        int cbv = (kf2 * 64 + fq * 16) ^ ((d & 7) << 4);
        bf16x8 vfr = as_bf(*(const short8*)(Vb + d * 128 + cbv));
        acco[nd] = mfma16(pa, vfr, acco[nd]);
      }
    }
    __builtin_amdgcn_s_setprio(0);
    __syncthreads();
    cur ^= 1;
  }

  // epilogue: ctx[b][s][h][d]
  const int b = bh >> 4, h = bh & 15;
#pragma unroll
  for (int j = 0; j < 4; ++j) {
    float inv = 1.f / l_run[j];
    int s = q0 + wave * 16 + fq * 4 + j;
#pragma unroll
    for (int nd = 0; nd < 8; ++nd) {
      int d = nd * 16 + fr;
      ctx[(((size_t)b * 2048 + s) * 16 + h) * 128 + d] = f2bf(acco[nd][j] * inv);
    }
  }
}

// ---------------------------------------------------------------------------
extern "C" void kernel_launch(void* const* d_in, const int* in_sizes, int n_in,
                              void* d_out, int out_size, void* d_ws, size_t ws_size,
                              hipStream_t stream)
{
  (void)in_sizes; (void)n_in; (void)out_size; (void)ws_size;
  const float* x       = (const float*)d_in[0];
  const float* w_qkv   = (const float*)d_in[1];
  const float* b_qkv   = (const float*)d_in[2];
  const float* w_dense = (const float*)d_in[3];
  const float* b_dense = (const float*)d_in[4];
  float* out = (float*)d_out;

  char* ws = (char*)d_ws;
  __hip_bfloat16* x_bf     = (__hip_bfloat16*)(ws);                  // 4096x2048   = 16MB
  __hip_bfloat16* wqkv_t   = (__hip_bfloat16*)(ws + 16777216);       // 6144x2048   = 24MB
  __hip_bfloat16* wdense_t = (__hip_bfloat16*)(ws + 41943040);       // 2048x2048   = 8MB
  __hip_bfloat16* qb       = (__hip_bfloat16*)(ws + 50331648);       // [32][2048][128] = 16MB
  __hip_bfloat16* kb       = (__hip_bfloat16*)(ws + 67108864);       // [32][2048][128] = 16MB
  __hip_bfloat16* vtb      = (__hip_bfloat16*)(ws + 83886080);       // [32][128][2048] = 16MB
  __hip_bfloat16* ctx      = (__hip_bfloat16*)(ws + 100663296);      // [4096][2048] = 16MB

  cvt_f32_bf16<<<4096, 256, 0, stream>>>(x, x_bf, 4096 * 2048);
  transpose_cvt<<<dim3(96, 32), 256, 0, stream>>>(w_qkv, wqkv_t, 2048, 6144);
  transpose_cvt<<<dim3(32, 32), 256, 0, stream>>>(w_dense, wdense_t, 2048, 2048);
  gemm_bt<<<dim3(48, 32), 256, 0, stream>>>(x_bf, wqkv_t, b_qkv, nullptr,
                                            qb, kb, vtb, 4096, 6144, 2048, 1);
  attn_kernel<<<1024, 256, 0, stream>>>(qb, kb, vtb, ctx);
  gemm_bt<<<dim3(16, 32), 256, 0, stream>>>(ctx, wdense_t, b_dense, out,
                                            nullptr, nullptr, nullptr, 4096, 2048, 2048, 0);
}